// Round 1
// 142.320 us; speedup vs baseline: 1.1148x; 1.1148x over previous
//
#include <hip/hip_runtime.h>
#include <hip/hip_bf16.h>

// QuantisedMonDEQ: n=512, d=784, B=128, C=10. All inputs/outputs float32.
// z_{t+1} = relu(0.5 z + 0.5 (Wq z + Ux)), 40 iters; logits = z*^T Wc^T + bc.
//
// INT8 formulation: Wq = sW*Q, Q = rint(W/sW) exact int8. z held as Q4.11
// fixed point v (int16), split v = 256*zh + (zlm+128), zh,zlm int8.
//   Q.v = 256*(Q.zh) + Q.zlm + 128*rowsum(Q)   (rowsum folded into Ux).
// Iters 1..27: hi-plane only; iters 28..39 both planes. z (fp32) + Ux fold
// live in registers per lane; LDS carries only the int8 B-plane transpose.
// Rowsum computed in-register via ones-vector i8 MFMA (no global buffer).
// Epilogue pack: v_cvt_pk_i16_i32 (saturating, subsumes min(,32767)) +
// v_perm_b32 byte extraction replaces the mul/rndne/cvt/min + shift/or chain.
// prep: x hi/lo staged in LDS via float4 loads (55.8KB -> 2 blocks/CU, one
// round); U fragments quantized on the fly from global.

#define N_DIM 512
#define D_DIM 784
#define B_DIM 128
#define C_DIM 10
#define QMAX 127.0f
#define N_ITERS 40
#define HILO_START 28
#define ZPITCH 528     // bytes per column plane row; 16B-aligned
#define MT 4           // 16-row M-tiles per wave
#define UPITCH 808     // bf16 elems per staged x row (800 data+pad), 16B-aligned

typedef int    i32x4  __attribute__((ext_vector_type(4)));
typedef float  f32x4  __attribute__((ext_vector_type(4)));
typedef __bf16 bf16x8 __attribute__((ext_vector_type(8)));
typedef short  s16x2  __attribute__((ext_vector_type(2)));

__device__ __forceinline__ float pscale64(const float* __restrict__ p) {
    float m = 0.0f;
#pragma unroll 16
    for (int i = 0; i < 64; ++i) m = fmaxf(m, p[i]);
    return m * (1.0f / QMAX);
}

// vq[0..3] (>=0) -> saturate to i16, h = hi bytes, l = lo bytes ^ 0x80.
__device__ __forceinline__ void pack_hl(const int vq[4], unsigned int& h, unsigned int& l) {
    int pk01, pk23;
#if __has_builtin(__builtin_amdgcn_cvt_pk_i16)
    union { s16x2 v; int i; } u0, u1;
    u0.v = __builtin_amdgcn_cvt_pk_i16(vq[0], vq[1]);
    u1.v = __builtin_amdgcn_cvt_pk_i16(vq[2], vq[3]);
    pk01 = u0.i; pk23 = u1.i;
#else
    asm("v_cvt_pk_i16_i32 %0, %1, %2" : "=v"(pk01) : "v"(vq[0]), "v"(vq[1]));
    asm("v_cvt_pk_i16_i32 %0, %1, %2" : "=v"(pk23) : "v"(vq[2]), "v"(vq[3]));
#endif
    h = __builtin_amdgcn_perm((unsigned int)pk23, (unsigned int)pk01, 0x07050301u);
    l = __builtin_amdgcn_perm((unsigned int)pk23, (unsigned int)pk01, 0x06040200u) ^ 0x80808080u;
}

// ---------------- per-block partial max|.| ----------------
__global__ void maxabs_kernel(const float* __restrict__ W,
                              const float* __restrict__ U,
                              const float* __restrict__ b,
                              float* __restrict__ partials) {
    const float4* src;
    int n4;
    if (blockIdx.y == 0)      { src = (const float4*)W; n4 = N_DIM * N_DIM / 4; }
    else if (blockIdx.y == 1) { src = (const float4*)U; n4 = N_DIM * D_DIM / 4; }
    else                      { src = (const float4*)b; n4 = N_DIM / 4; }
    float m = 0.0f;
    for (int i = blockIdx.x * blockDim.x + threadIdx.x; i < n4; i += gridDim.x * blockDim.x) {
        float4 v = src[i];
        m = fmaxf(m, fmaxf(fmaxf(fabsf(v.x), fabsf(v.y)), fmaxf(fabsf(v.z), fabsf(v.w))));
    }
    __shared__ float red[256];
    red[threadIdx.x] = m;
    __syncthreads();
    for (int s = 128; s > 0; s >>= 1) {
        if (threadIdx.x < s) red[threadIdx.x] = fmaxf(red[threadIdx.x], red[threadIdx.x + s]);
        __syncthreads();
    }
    if (threadIdx.x == 0) partials[blockIdx.y * 64 + blockIdx.x] = red[0];
}

// -------- prep: blocks 0..255 quantW(int8); 256..511 uxT (x-only LDS) --------
__global__ __launch_bounds__(256) void prep_kernel(const float* __restrict__ W,
                                                   const float* __restrict__ U,
                                                   const float* __restrict__ b,
                                                   const float* __restrict__ x,
                                                   const float* __restrict__ partials,
                                                   signed char* __restrict__ Qp8,
                                                   float* __restrict__ UxT) {
    __shared__ __bf16 xhS[16][UPITCH];
    __shared__ __bf16 xlS[16][UPITCH];
    __shared__ f32x4  sacc[4][64];
    const int t = threadIdx.x;
    if (blockIdx.x < 256) {
        // ---- W quant (2 rows per block), no rowsum (solve derives it) ----
        const float s = pscale64(partials);
        const float inv = 1.0f / s;
        int idx = blockIdx.x * 256 + t;            // float4 index into W
        float4 w = ((const float4*)W)[idx];
        int k = (idx << 2) & (N_DIM - 1);
        int r = (idx << 2) >> 9;
        char4 c;
        c.x = (signed char)(int)rintf(w.x * inv);
        c.y = (signed char)(int)rintf(w.y * inv);
        c.z = (signed char)(int)rintf(w.z * inv);
        c.w = (signed char)(int)rintf(w.w * inv);
        int kc = k >> 6, q = (k >> 4) & 3, jj = k & 15;
        *(char4*)&Qp8[((kc << 9) + r) * 64 + q * 16 + jj] = c;
    } else {
        // ---- UxT[c][i] = bq[i] + sU * sum_d Qu[i][d]*x[c][d] ----
        const float sU = pscale64(partials + 64);
        const float invU = 1.0f / sU;
        const float sb = pscale64(partials + 128);
        const int bx = blockIdx.x - 256;           // 0..255
        const int i0 = (bx >> 3) * 16;             // U-row tile base (32 groups)
        const int c0 = (bx & 7) * 16;              // batch-col tile base (8 groups)
        // vectorized x staging: hi/lo bf16 split, float4 loads
        for (int i = t; i < 16 * 196; i += 256) {
            int r = i / 196, kf = i - r * 196;
            float4 v = *(const float4*)&x[(c0 + r) * D_DIM + (kf << 2)];
            union { __bf16 e[4]; ushort4 u; } hh, ll;
            float f0 = v.x, f1 = v.y, f2 = v.z, f3 = v.w;
            __bf16 h0 = (__bf16)f0, h1 = (__bf16)f1, h2 = (__bf16)f2, h3 = (__bf16)f3;
            hh.e[0] = h0; hh.e[1] = h1; hh.e[2] = h2; hh.e[3] = h3;
            ll.e[0] = (__bf16)(f0 - (float)h0);
            ll.e[1] = (__bf16)(f1 - (float)h1);
            ll.e[2] = (__bf16)(f2 - (float)h2);
            ll.e[3] = (__bf16)(f3 - (float)h3);
            *(ushort4*)&xhS[r][kf << 2] = hh.u;
            *(ushort4*)&xlS[r][kf << 2] = ll.u;
        }
        // zero-fill pad k in [784, 800)
        {
            int r = t >> 4, k = D_DIM + (t & 15);
            xhS[r][k] = (__bf16)0.0f; xlS[r][k] = (__bf16)0.0f;
        }
        __syncthreads();
        const int wave = t >> 6, lane = t & 63;
        const int m = lane & 15, quad = lane >> 4;
        f32x4 acc = {};
        for (int kc = wave; kc < 25; kc += 4) {
            const int k0 = (kc << 5) + (quad << 3);
            bf16x8 au = {};
            if (k0 < D_DIM) {   // kc==24 only quads 0,1 valid (784 = 24*32+16)
                const float4 u0 = *(const float4*)&U[(i0 + m) * D_DIM + k0];
                const float4 u1 = *(const float4*)&U[(i0 + m) * D_DIM + k0 + 4];
                au[0] = (__bf16)rintf(u0.x * invU); au[1] = (__bf16)rintf(u0.y * invU);
                au[2] = (__bf16)rintf(u0.z * invU); au[3] = (__bf16)rintf(u0.w * invU);
                au[4] = (__bf16)rintf(u1.x * invU); au[5] = (__bf16)rintf(u1.y * invU);
                au[6] = (__bf16)rintf(u1.z * invU); au[7] = (__bf16)rintf(u1.w * invU);
            }
            bf16x8 bh = *(const bf16x8*)&xhS[m][k0];
            bf16x8 bl = *(const bf16x8*)&xlS[m][k0];
            acc = __builtin_amdgcn_mfma_f32_16x16x32_bf16(au, bh, acc, 0, 0, 0);
            acc = __builtin_amdgcn_mfma_f32_16x16x32_bf16(au, bl, acc, 0, 0, 0);
        }
        sacc[wave][lane] = acc;
        __syncthreads();
        if (wave == 0) {
            f32x4 s0 = sacc[0][lane], s1 = sacc[1][lane];
            f32x4 s2 = sacc[2][lane], s3 = sacc[3][lane];
            const int row0 = i0 + (quad << 2);
            f32x4 o;
#pragma unroll
            for (int r = 0; r < 4; ++r)
                o[r] = sU * (s0[r] + s1[r] + s2[r] + s3[r])
                     + rintf(b[row0 + r] / sb) * sb;
            *(f32x4*)&UxT[(c0 + m) * N_DIM + row0] = o;
        }
    }
}

// ---------------- fused int8-MFMA solve + logits ----------------
__global__ __launch_bounds__(512, 2) void solve_kernel(const signed char* __restrict__ Qp8,
                                                       const float* __restrict__ UxT,
                                                       const float* __restrict__ partials,
                                                       const float* __restrict__ Wc,
                                                       const float* __restrict__ bc,
                                                       float* __restrict__ out) {
    __shared__ signed char zh[2][16][ZPITCH];
    __shared__ signed char zl[2][16][ZPITCH];
    __shared__ float red[32][16][C_DIM];
    const int t = threadIdx.x;
    const int wave = t >> 6;
    const int lane = t & 63;
    const int m = lane & 15;      // batch col within block tile
    const int quad = lane >> 4;   // D-row group
    const int c0 = blockIdx.x * 16;
    const float sW = pscale64(partials);
    const float c1 = sW * (1.0f / 2048.0f);
    const float hc_hi = c1 * 128.0f;     // 0.5 * c1 * 256
    const float hc_lo = c1 * 0.5f;
    const int rowbase = wave * 64;

    // register/AGPR-resident A fragments: 8 kc x 4 M-tiles x 16B
    i32x4 A[MT][8];
#pragma unroll
    for (int ti = 0; ti < MT; ++ti)
#pragma unroll
        for (int kc = 0; kc < 8; ++kc)
            A[ti][kc] = *(const i32x4*)&Qp8[((kc << 9) + rowbase + ti * 16 + m) * 64 + (quad << 4)];

    // rowsum(Q) per row via ones-vector i8 MFMA (exact int; layout matches C)
    const i32x4 onesb = {0x01010101, 0x01010101, 0x01010101, 0x01010101};
    i32x4 rs[MT];
#pragma unroll
    for (int ti = 0; ti < MT; ++ti) {
        i32x4 a = {};
#pragma unroll
        for (int kc = 0; kc < 8; ++kc)
            a = __builtin_amdgcn_mfma_i32_16x16x64_i8(A[ti][kc], onesb, a, 0, 0, 0);
        rs[ti] = a;
    }

    // prologue: per-lane z1 = relu(0.5*Ux), Ux-fold in registers, zh[0] plane
    float zreg[MT][4];
    float uxh[MT][4];
#pragma unroll
    for (int ti = 0; ti < MT; ++ti) {
        const int row0 = rowbase + ti * 16 + (quad << 2);
        const f32x4 v4 = *(const f32x4*)&UxT[(c0 + m) * N_DIM + row0];
        int vq[4];
#pragma unroll
        for (int r = 0; r < 4; ++r) {
            const float v = v4[r];
            uxh[ti][r] = 0.5f * (v + hc_hi * (float)rs[ti][r]);
            const float z1 = fmaxf(0.5f * v, 0.0f);
            zreg[ti][r] = z1;
            vq[r] = (int)rintf(z1 * 2048.0f);
        }
        unsigned int h, l;
        pack_hl(vq, h, l);
        *(unsigned int*)&zh[0][m][row0] = h;
        *(unsigned int*)&zl[0][m][row0] = l;
    }

#pragma unroll
    for (int ti = 0; ti < MT; ++ti)
#pragma unroll
        for (int kc = 0; kc < 8; ++kc)
            asm volatile("" : "+v"(A[ti][kc]));
    __syncthreads();

    int cur = 0;
    for (int it = 1; it < N_ITERS; ++it) {
        const bool lo = (it >= HILO_START);
        const bool wlo = (it >= HILO_START - 1);
        i32x4 acch[MT] = {};
        i32x4 accl[MT] = {};
        if (lo) {
#pragma unroll
            for (int kc = 0; kc < 8; ++kc) {
                i32x4 bh = *(const i32x4*)&zh[cur][m][(kc << 6) + (quad << 4)];
                i32x4 bl = *(const i32x4*)&zl[cur][m][(kc << 6) + (quad << 4)];
#pragma unroll
                for (int ti = 0; ti < MT; ++ti) {
                    acch[ti] = __builtin_amdgcn_mfma_i32_16x16x64_i8(A[ti][kc], bh, acch[ti], 0, 0, 0);
                    accl[ti] = __builtin_amdgcn_mfma_i32_16x16x64_i8(A[ti][kc], bl, accl[ti], 0, 0, 0);
                }
            }
        } else {
#pragma unroll
            for (int kc = 0; kc < 8; ++kc) {
                i32x4 bh = *(const i32x4*)&zh[cur][m][(kc << 6) + (quad << 4)];
#pragma unroll
                for (int ti = 0; ti < MT; ++ti)
                    acch[ti] = __builtin_amdgcn_mfma_i32_16x16x64_i8(A[ti][kc], bh, acch[ti], 0, 0, 0);
            }
        }
        const int nxt = cur ^ 1;
#pragma unroll
        for (int ti = 0; ti < MT; ++ti) {
            const int row0 = rowbase + ti * 16 + (quad << 2);
            int vq[4];
#pragma unroll
            for (int r = 0; r < 4; ++r) {
                float base = fmaf(0.5f, zreg[ti][r], uxh[ti][r]);
                float u = lo ? fmaf(hc_hi, (float)acch[ti][r], fmaf(hc_lo, (float)accl[ti][r], base))
                             : fmaf(hc_hi, (float)acch[ti][r], base);
                float zn = fmaxf(u, 0.0f);
                zreg[ti][r] = zn;
                vq[r] = (int)rintf(zn * 2048.0f);
            }
            unsigned int h, l;
            pack_hl(vq, h, l);
            *(unsigned int*)&zh[nxt][m][row0] = h;
            if (wlo) *(unsigned int*)&zl[nxt][m][row0] = l;
        }
        __syncthreads();
        cur = nxt;
    }

    // ---- fused logits from register z ----
    {
        const int grp = wave * 4 + quad;   // 0..31
        float p[C_DIM];
#pragma unroll
        for (int cl = 0; cl < C_DIM; ++cl) p[cl] = 0.0f;
#pragma unroll
        for (int ti = 0; ti < MT; ++ti) {
            const int row0 = rowbase + ti * 16 + (quad << 2);
#pragma unroll
            for (int r = 0; r < 4; ++r) {
                float zv = zreg[ti][r];
#pragma unroll
                for (int cl = 0; cl < C_DIM; ++cl)
                    p[cl] += zv * Wc[cl * N_DIM + row0 + r];
            }
        }
#pragma unroll
        for (int cl = 0; cl < C_DIM; ++cl) red[grp][m][cl] = p[cl];
        __syncthreads();
        for (int s = 16; s > 0; s >>= 1) {
            if (grp < s) {
#pragma unroll
                for (int cl = 0; cl < C_DIM; ++cl)
                    red[grp][m][cl] += red[grp + s][m][cl];
            }
            __syncthreads();
        }
        if (t < 16 * C_DIM) {
            int col = t & 15;
            int cl  = t >> 4;
            out[(c0 + col) * C_DIM + cl] = red[0][col][cl] + bc[cl];
        }
    }
}

extern "C" void kernel_launch(void* const* d_in, const int* in_sizes, int n_in,
                              void* d_out, int out_size, void* d_ws, size_t ws_size,
                              hipStream_t stream) {
    const float* W  = (const float*)d_in[0];
    const float* U  = (const float*)d_in[1];
    const float* b  = (const float*)d_in[2];
    const float* x  = (const float*)d_in[3];
    const float* Wc = (const float*)d_in[4];
    const float* bc = (const float*)d_in[5];
    float* out = (float*)d_out;

    float* ws = (float*)d_ws;
    float* partials = ws;                               // 3*64 floats (+pad to 256)
    signed char* Qp8 = (signed char*)(ws + 256);        // 512x512 int8, [kc][r][64B]
    float* UxT = ws + 256 + (N_DIM * N_DIM / 4);        // 128x512 fp32

    maxabs_kernel<<<dim3(64, 3), 256, 0, stream>>>(W, U, b, partials);
    prep_kernel<<<512, 256, 0, stream>>>(W, U, b, x, partials, Qp8, UxT);
    solve_kernel<<<8, 512, 0, stream>>>(Qp8, UxT, partials, Wc, bc, out);
}